// Round 7
// baseline (112.722 us; speedup 1.0000x reference)
//
#include <hip/hip_runtime.h>
#include <math.h>

#define N_SQ   7          // 7 squarings -> A^128; Frobenius -> trace(A^256)
#define INV_P  (1.0f / 256.0f)
#define EPS_F  1e-20f
#define PH     72         // f16 pitch for staged 64-row planes
#define PQ     67         // f32 pitch for Q1 transpose buffer

typedef _Float16 h2    __attribute__((ext_vector_type(2)));
typedef _Float16 f16x8 __attribute__((ext_vector_type(8)));
typedef float    f32x4 __attribute__((ext_vector_type(4)));

__device__ inline float cdot2(h2 a, h2 b, float c) {
#if __has_builtin(__builtin_amdgcn_fdot2)
    return __builtin_amdgcn_fdot2(a, b, c, false);
#else
    return c + (float)a.x * (float)b.x + (float)a.y * (float)b.y;
#endif
}
__device__ inline h2 bch2(unsigned int x) { return __builtin_bit_cast(h2, x); }
__device__ inline h2 bch2f(float x)       { return __builtin_bit_cast(h2, x); }
__device__ inline float bcf(h2 x)         { return __builtin_bit_cast(float, x); }

// ws: raw res_final per (b,s): ws[bs*512 + g], 72*512 floats.

__global__ __launch_bounds__(512) __attribute__((amdgpu_waves_per_eu(2, 2)))
void ista_main_kernel(
    const float* __restrict__ Dre, const float* __restrict__ Dim,
    const float* __restrict__ Cre, const float* __restrict__ Cim,
    float* __restrict__ out, float* __restrict__ ws)
{
    const int bs = blockIdx.x;     // 0..71
    const int t  = threadIdx.x;    // 0..511
    const int wv = t >> 6;         // wave 0..7
    const int ln = t & 63;         // lane
    const int c16 = ln & 15;       // MFMA col / row-select
    const int qd  = ln >> 4;       // MFMA quad
    const float* __restrict__ dre = Dre + (size_t)bs * 32768;
    const float* __restrict__ dim = Dim + (size_t)bs * 32768;

    // Unified buffer: phases C/D: ShRe f16[64*PH] | ShIm f16[64*PH] | Q1 f32[64*PQ]
    // Phase E aliases: sUp f32[1024] | sHu f32[128] | sResH f16[512]
    __shared__ __align__(16) float uBuf[9216];          // 36864 B
    _Float16* ShRe = (_Float16*)uBuf;
    _Float16* ShIm = (_Float16*)uBuf + 64 * PH;
    float*    Q1   = uBuf + 4608;
    float*    sUp  = uBuf;                              // [0,1024) floats
    float*    sHu  = uBuf + 1024;                       // [1024,1152)
    _Float16* sResH = (_Float16*)(uBuf + 1152);         // 512 f16
    __shared__ __align__(16) float s_r[128];
    __shared__ float s_red[16];
    __shared__ float s_scal[8];  // 0=gamma 1=theta 2=max|Dhr| 3=E(log) 4=1/c 5=lo 6=hi 7=norm2

    // ---------------- Phase A: r = vec(C^T) ----------------
    if (t < 64) {
        int i = t >> 3, j = t & 7;
        s_r[2 * t]     = Cre[bs * 64 + j * 8 + i];
        s_r[2 * t + 1] = Cim[bs * 64 + j * 8 + i];
    }
    __syncthreads();

    // ---------------- Phase B: Dhr[g] + build dV column tile (same loads) ----------------
    float dhr_re = 0.f, dhr_im = 0.f;
    h2 dV[64];    // D[m][t] packed (re,im) f16
    #pragma unroll
    for (int m = 0; m < 64; ++m) {
        float ar = dre[m * 512 + t], ai = dim[m * 512 + t];
        dV[m] = h2{(_Float16)ar, (_Float16)ai};
        float rr = s_r[2 * m], ri = s_r[2 * m + 1];
        dhr_re += ar * rr + ai * ri;
        dhr_im += ar * ri - ai * rr;
    }
    {
        float sv = dhr_re * dhr_re;
        float mv = sqrtf(dhr_re * dhr_re + dhr_im * dhr_im);
        for (int off = 32; off; off >>= 1) {
            sv += __shfl_down(sv, off, 64);
            mv = fmaxf(mv, __shfl_down(mv, off, 64));
        }
        if (ln == 0) { s_red[wv] = sv; s_red[8 + wv] = mv; }
        __syncthreads();
        if (t == 0) {
            float ss = 0.f, mm = 0.f;
            for (int k = 0; k < 8; ++k) { ss += s_red[k]; mm = fmaxf(mm, s_red[8 + k]); }
            s_scal[7] = ss; s_scal[2] = mm;
        }
        __syncthreads();
    }
    float res_g = dhr_re / (sqrtf(s_scal[7]) + EPS_F);

    // ---------------- MFMA tile ownership ----------------
    const int tau0 = 2 * wv, tau1 = 2 * wv + 1;
    const int I0 = tau0 >> 2, J0 = tau0 & 3;
    const int I1 = tau1 >> 2, J1 = tau1 & 3;

    auto epilogue = [&](f32x4 P0, f32x4 Qa0, f32x4 P1, f32x4 Qa1, bool first, bool last) {
        #pragma unroll
        for (int r = 0; r < 4; ++r) {
            Q1[(I0 * 16 + qd * 4 + r) * PQ + J0 * 16 + c16] = Qa0[r];
            Q1[(I1 * 16 + qd * 4 + r) * PQ + J1 * 16 + c16] = Qa1[r];
        }
        float dv = 0.f;
        if (I0 == J0) {
            #pragma unroll
            for (int r = 0; r < 4; ++r) if (qd * 4 + r == c16) dv = fmaxf(dv, fabsf(P0[r]));
        }
        if (I1 == J1) {
            #pragma unroll
            for (int r = 0; r < 4; ++r) if (qd * 4 + r == c16) dv = fmaxf(dv, fabsf(P1[r]));
        }
        for (int off = 32; off; off >>= 1) dv = fmaxf(dv, __shfl_down(dv, off, 64));
        if (ln == 0) s_red[wv] = dv;
        __syncthreads();
        if (t == 0) {
            float m = 0.f;
            for (int k = 0; k < 8; ++k) m = fmaxf(m, s_red[k]);
            s_scal[3] = first ? logf(m) : 2.f * s_scal[3] + logf(m);
            s_scal[4] = 1.f / m;
        }
        __syncthreads();
        float ic = s_scal[4];
        float ci0[4], ci1[4];
        #pragma unroll
        for (int r = 0; r < 4; ++r) {
            ci0[r] = Qa0[r] - Q1[(J0 * 16 + c16) * PQ + I0 * 16 + qd * 4 + r];
            ci1[r] = Qa1[r] - Q1[(J1 * 16 + c16) * PQ + I1 * 16 + qd * 4 + r];
        }
        if (!last) {
            #pragma unroll
            for (int r = 0; r < 4; ++r) {
                ShRe[(I0 * 16 + qd * 4 + r) * PH + J0 * 16 + c16] = (_Float16)(P0[r] * ic);
                ShIm[(I0 * 16 + qd * 4 + r) * PH + J0 * 16 + c16] = (_Float16)(ci0[r] * ic);
                ShRe[(I1 * 16 + qd * 4 + r) * PH + J1 * 16 + c16] = (_Float16)(P1[r] * ic);
                ShIm[(I1 * 16 + qd * 4 + r) * PH + J1 * 16 + c16] = (_Float16)(ci1[r] * ic);
            }
            __syncthreads();
        } else {
            float fr = 0.f;
            #pragma unroll
            for (int r = 0; r < 4; ++r)
                fr += P0[r] * P0[r] + ci0[r] * ci0[r] + P1[r] * P1[r] + ci1[r] * ci1[r];
            fr *= ic * ic;
            for (int off = 32; off; off >>= 1) fr += __shfl_down(fr, off, 64);
            if (ln == 0) s_red[wv] = fr;
            __syncthreads();
            if (t == 0) {
                float fsum = 0.f;
                for (int k = 0; k < 8; ++k) fsum += s_red[k];
                float loglam = (2.f * s_scal[3] + logf(fsum)) * INV_P;
                float gamma = expf(-loglam);
                s_scal[0] = gamma;
                s_scal[1] = 0.5f * s_scal[2] * gamma;
            }
            __syncthreads();
        }
    };

    // ---------------- Phase C: Gram via MFMA; grab dU row tile when ch==wv ----------------
    h2 du_re[32], du_im[32];   // g-pairs of row ln, g in [64wv, 64wv+64)
    f32x4 gP0 = {0.f, 0.f, 0.f, 0.f}, gQ0 = {0.f, 0.f, 0.f, 0.f};
    f32x4 gP1 = {0.f, 0.f, 0.f, 0.f}, gQ1 = {0.f, 0.f, 0.f, 0.f};
    {
        const int srow = t >> 4;          // 0..31
        const int scb  = (t & 15) * 4;    // col base in chunk
        float4 pr0, pi0, pr1, pi1;
        pr0 = *(const float4*)&dre[srow * 512 + scb];
        pi0 = *(const float4*)&dim[srow * 512 + scb];
        pr1 = *(const float4*)&dre[(srow + 32) * 512 + scb];
        pi1 = *(const float4*)&dim[(srow + 32) * 512 + scb];
        for (int ch = 0; ch < 8; ++ch) {
            *(h2*)&ShRe[srow * PH + scb]     = h2{(_Float16)pr0.x, (_Float16)pr0.y};
            *(h2*)&ShRe[srow * PH + scb + 2] = h2{(_Float16)pr0.z, (_Float16)pr0.w};
            *(h2*)&ShIm[srow * PH + scb]     = h2{(_Float16)pi0.x, (_Float16)pi0.y};
            *(h2*)&ShIm[srow * PH + scb + 2] = h2{(_Float16)pi0.z, (_Float16)pi0.w};
            *(h2*)&ShRe[(srow + 32) * PH + scb]     = h2{(_Float16)pr1.x, (_Float16)pr1.y};
            *(h2*)&ShRe[(srow + 32) * PH + scb + 2] = h2{(_Float16)pr1.z, (_Float16)pr1.w};
            *(h2*)&ShIm[(srow + 32) * PH + scb]     = h2{(_Float16)pi1.x, (_Float16)pi1.y};
            *(h2*)&ShIm[(srow + 32) * PH + scb + 2] = h2{(_Float16)pi1.z, (_Float16)pi1.w};
            if (ch < 7) {
                int gc = (ch + 1) * 64;
                pr0 = *(const float4*)&dre[srow * 512 + gc + scb];
                pi0 = *(const float4*)&dim[srow * 512 + gc + scb];
                pr1 = *(const float4*)&dre[(srow + 32) * 512 + gc + scb];
                pi1 = *(const float4*)&dim[(srow + 32) * 512 + gc + scb];
            }
            __syncthreads();
            #pragma unroll
            for (int ks = 0; ks < 64; ks += 32) {
                f16x8 arI0 = *(const f16x8*)&ShRe[(I0 * 16 + c16) * PH + ks + qd * 8];
                f16x8 aiI0 = *(const f16x8*)&ShIm[(I0 * 16 + c16) * PH + ks + qd * 8];
                f16x8 arJ0 = *(const f16x8*)&ShRe[(J0 * 16 + c16) * PH + ks + qd * 8];
                f16x8 aiJ0 = *(const f16x8*)&ShIm[(J0 * 16 + c16) * PH + ks + qd * 8];
                gP0 = __builtin_amdgcn_mfma_f32_16x16x32_f16(arI0, arJ0, gP0, 0, 0, 0);
                gP0 = __builtin_amdgcn_mfma_f32_16x16x32_f16(aiI0, aiJ0, gP0, 0, 0, 0);
                gQ0 = __builtin_amdgcn_mfma_f32_16x16x32_f16(aiI0, arJ0, gQ0, 0, 0, 0);
                f16x8 arI1 = *(const f16x8*)&ShRe[(I1 * 16 + c16) * PH + ks + qd * 8];
                f16x8 aiI1 = *(const f16x8*)&ShIm[(I1 * 16 + c16) * PH + ks + qd * 8];
                f16x8 arJ1 = *(const f16x8*)&ShRe[(J1 * 16 + c16) * PH + ks + qd * 8];
                f16x8 aiJ1 = *(const f16x8*)&ShIm[(J1 * 16 + c16) * PH + ks + qd * 8];
                gP1 = __builtin_amdgcn_mfma_f32_16x16x32_f16(arI1, arJ1, gP1, 0, 0, 0);
                gP1 = __builtin_amdgcn_mfma_f32_16x16x32_f16(aiI1, aiJ1, gP1, 0, 0, 0);
                gQ1 = __builtin_amdgcn_mfma_f32_16x16x32_f16(aiI1, arJ1, gQ1, 0, 0, 0);
            }
            if (ch == wv) {
                #pragma unroll
                for (int c = 0; c < 8; ++c) {
                    uint4 aw = *(const uint4*)&ShRe[ln * PH + 8 * c];
                    du_re[4 * c + 0] = bch2(aw.x); du_re[4 * c + 1] = bch2(aw.y);
                    du_re[4 * c + 2] = bch2(aw.z); du_re[4 * c + 3] = bch2(aw.w);
                    uint4 bw = *(const uint4*)&ShIm[ln * PH + 8 * c];
                    du_im[4 * c + 0] = bch2(bw.x); du_im[4 * c + 1] = bch2(bw.y);
                    du_im[4 * c + 2] = bch2(bw.z); du_im[4 * c + 3] = bch2(bw.w);
                }
            }
            __syncthreads();
        }
    }
    epilogue(gP0, gQ0, gP1, gQ1, true, false);

    // ---------------- Phase D: 7 scaled squarings via MFMA ----------------
    for (int sq = 0; sq < N_SQ; ++sq) {
        f32x4 P0 = {0.f, 0.f, 0.f, 0.f}, Qa0 = {0.f, 0.f, 0.f, 0.f};
        f32x4 P1 = {0.f, 0.f, 0.f, 0.f}, Qa1 = {0.f, 0.f, 0.f, 0.f};
        #pragma unroll
        for (int ks = 0; ks < 64; ks += 32) {
            f16x8 arI0 = *(const f16x8*)&ShRe[(I0 * 16 + c16) * PH + ks + qd * 8];
            f16x8 aiI0 = *(const f16x8*)&ShIm[(I0 * 16 + c16) * PH + ks + qd * 8];
            f16x8 arJ0 = *(const f16x8*)&ShRe[(J0 * 16 + c16) * PH + ks + qd * 8];
            f16x8 aiJ0 = *(const f16x8*)&ShIm[(J0 * 16 + c16) * PH + ks + qd * 8];
            P0  = __builtin_amdgcn_mfma_f32_16x16x32_f16(arI0, arJ0, P0, 0, 0, 0);
            P0  = __builtin_amdgcn_mfma_f32_16x16x32_f16(aiI0, aiJ0, P0, 0, 0, 0);
            Qa0 = __builtin_amdgcn_mfma_f32_16x16x32_f16(aiI0, arJ0, Qa0, 0, 0, 0);
            f16x8 arI1 = *(const f16x8*)&ShRe[(I1 * 16 + c16) * PH + ks + qd * 8];
            f16x8 aiI1 = *(const f16x8*)&ShIm[(I1 * 16 + c16) * PH + ks + qd * 8];
            f16x8 arJ1 = *(const f16x8*)&ShRe[(J1 * 16 + c16) * PH + ks + qd * 8];
            f16x8 aiJ1 = *(const f16x8*)&ShIm[(J1 * 16 + c16) * PH + ks + qd * 8];
            P1  = __builtin_amdgcn_mfma_f32_16x16x32_f16(arI1, arJ1, P1, 0, 0, 0);
            P1  = __builtin_amdgcn_mfma_f32_16x16x32_f16(aiI1, aiJ1, P1, 0, 0, 0);
            Qa1 = __builtin_amdgcn_mfma_f32_16x16x32_f16(aiI1, arJ1, Qa1, 0, 0, 0);
        }
        epilogue(P0, Qa0, P1, Qa1, false, sq == N_SQ - 1);
    }

    // ---------------- Phase E: 16 ISTA layers, shuffle-free ----------------
    const float gamma = s_scal[0];
    const float theta = s_scal[1];
    float* out_init = out + 40960 + (size_t)bs * 8192;
    const int resh_base = 64 * wv;

    for (int l = 0; l < 16; ++l) {
        sResH[t] = (_Float16)res_g;          // read back only by own wave
        float upR = 0.f, upI = 0.f;
        #pragma unroll
        for (int c = 0; c < 8; ++c) {
            uint4 rw = *(const uint4*)&sResH[resh_base + 8 * c];
            h2 r0 = bch2(rw.x), r1 = bch2(rw.y), r2 = bch2(rw.z), r3 = bch2(rw.w);
            upR = cdot2(du_re[4 * c + 0], r0, upR);  upI = cdot2(du_im[4 * c + 0], r0, upI);
            upR = cdot2(du_re[4 * c + 1], r1, upR);  upI = cdot2(du_im[4 * c + 1], r1, upI);
            upR = cdot2(du_re[4 * c + 2], r2, upR);  upI = cdot2(du_im[4 * c + 2], r2, upI);
            upR = cdot2(du_re[4 * c + 3], r3, upR);  upI = cdot2(du_im[4 * c + 3], r3, upI);
        }
        *(float2*)&sUp[(wv * 64 + ln) * 2] = make_float2(upR, upI);
        __syncthreads();
        if (wv == 0) {
            float ufR = 0.f, ufI = 0.f;
            #pragma unroll
            for (int w8 = 0; w8 < 8; ++w8) {
                float2 p = *(const float2*)&sUp[(w8 * 64 + ln) * 2];
                ufR += p.x; ufI += p.y;
            }
            h2 hu1 = h2{(_Float16)ufR, (_Float16)ufI};
            h2 hu2 = h2{(_Float16)ufI, (_Float16)(-ufR)};
            *(float2*)&sHu[2 * ln] = make_float2(bcf(hu1), bcf(hu2));
        }
        __syncthreads();
        float wR = 0.f, wI = 0.f;
        #pragma unroll
        for (int mm = 0; mm < 32; ++mm) {
            float4 hq = *(const float4*)&sHu[4 * mm];
            wR = cdot2(dV[2 * mm],     bch2f(hq.x), wR);
            wI = cdot2(dV[2 * mm],     bch2f(hq.y), wI);
            wR = cdot2(dV[2 * mm + 1], bch2f(hq.z), wR);
            wI = cdot2(dV[2 * mm + 1], bch2f(hq.w), wI);
        }
        float sre = res_g + gamma * (dhr_re - wR);
        float sim = gamma * (dhr_im - wI);
        float mag = sqrtf(sre * sre + sim * sim);
        res_g = fmaxf(mag - theta, 0.f);
        out_init[l * 512 + t] = res_g;
    }

    // ---------------- Phase F: epilogue ----------------
    {
        float mn = res_g, mx = res_g;
        for (int off = 32; off; off >>= 1) {
            mn = fminf(mn, __shfl_down(mn, off, 64));
            mx = fmaxf(mx, __shfl_down(mx, off, 64));
        }
        if (ln == 0) { s_red[wv] = mn; s_red[8 + wv] = mx; }
        __syncthreads();
        if (t == 0) {
            float a = s_red[0], b2 = s_red[8];
            for (int k = 1; k < 8; ++k) { a = fminf(a, s_red[k]); b2 = fmaxf(b2, s_red[8 + k]); }
            s_scal[5] = a; s_scal[6] = b2;
        }
        __syncthreads();
        out[bs * 512 + t] = (res_g - s_scal[5]) / (s_scal[6] - s_scal[5] + EPS_F);
        ws[bs * 512 + t] = res_g;
    }
}

__global__ __launch_bounds__(512) void ista_ave_kernel(
    const float* __restrict__ ws, float* __restrict__ out)
{
    const int b = blockIdx.x;    // 0..7
    const int g = threadIdx.x;   // 0..511
    __shared__ float s_red[16];
    __shared__ float s_scal[2];
    float acc = 0.f;
    #pragma unroll
    for (int s = 0; s < 9; ++s) acc += ws[(b * 9 + s) * 512 + g];
    acc *= (1.f / 9.f);
    float mn = acc, mx = acc;
    for (int off = 32; off; off >>= 1) {
        mn = fminf(mn, __shfl_down(mn, off, 64));
        mx = fmaxf(mx, __shfl_down(mx, off, 64));
    }
    if ((g & 63) == 0) { s_red[g >> 6] = mn; s_red[8 + (g >> 6)] = mx; }
    __syncthreads();
    if (g == 0) {
        float a = s_red[0], b2 = s_red[8];
        for (int k = 1; k < 8; ++k) { a = fminf(a, s_red[k]); b2 = fmaxf(b2, s_red[8 + k]); }
        s_scal[0] = a; s_scal[1] = b2;
    }
    __syncthreads();
    out[36864 + b * 512 + g] = (acc - s_scal[0]) / (s_scal[1] - s_scal[0] + EPS_F);
}

extern "C" void kernel_launch(void* const* d_in, const int* in_sizes, int n_in,
                              void* d_out, int out_size, void* d_ws, size_t ws_size,
                              hipStream_t stream) {
    const float* Dre = (const float*)d_in[0];
    const float* Dim = (const float*)d_in[1];
    const float* Cre = (const float*)d_in[2];
    const float* Cim = (const float*)d_in[3];
    float* out = (float*)d_out;
    float* ws  = (float*)d_ws;

    ista_main_kernel<<<72, 512, 0, stream>>>(Dre, Dim, Cre, Cim, out, ws);
    ista_ave_kernel<<<8, 512, 0, stream>>>(ws, out);
}